// Round 5
// baseline (318.517 us; speedup 1.0000x reference)
//
#include <hip/hip_runtime.h>
#include <math.h>

#define HN       250
#define WN       400
#define N_RAYS   (HN * WN)        // 100000
#define N_SAMP   1000000
#define P_TENSO  50000
#define STEP_SZ  0.005f
#define DENS_SCALE 1.0f           // min(1/(1-0), 25) = 1
#define NB_SCAN  ((P_TENSO + 1023) / 1024)   // 49
#define NB_GATHER 2048
#define NW_GATHER (NB_GATHER * 4)            // 8192 persistent waves

// NOTE (R7): cooperative grid.sync() ~100 us/sync on MI355X — don't re-fuse
// with a full-grid barrier. 49-block co-resident spin barriers are fine.
// NOTE (R8): each returning atomicAdd costs a 64B line transaction.
// NOTE (R9/R10): gather is LATENCY-bound; 32B-packed random loads and scatter
// stores are free INSIDE gather; scattered partial-line stores in a thin
// kernel cost 2-4x traffic (RMW); 2x sample unroll HURT (VGPR/occ).
// NOTE (R11): random loads are only free when LINE-EFFICIENT (packed 32B).
// NOTE (R12): best-of composition == R0 time; pipeline pinned ~278us with
// gather 62 and everything else <61 => latency/overhead, not BW. R13:
// persistent-wave gather (hide stage latency), merge scan+finalize.

// ---------------- workspace layout (bytes) ----------------
#define OFF_PACK    0            // 1M x 32B sample structs, original (n) order
#define OFF_RESULTS 32000000     // 1M x 16B (lt,r,g,b), ORIGINAL (n) order
#define OFF_PERM    48000000     // 1M int, pos -> n
#define OFF_RT      52000000     // 1M int, (tid<<16)|rank
#define OFF_CURSOR  56000000     // 50K int (atomic counters == final counts)
#define OFF_STARTS  56200000     // (P_TENSO+1) int exclusive scan
#define OFF_BSUMS   56400064     // 64 int
#define OFF_FLAG    56400512     // 2 ints (spin-barrier arrivals)
#define OFF_RSTART  56401024     // (N_RAYS+1) int
#define WS_NEED     (56401024 + 400004 + 64)

// gather slab layout (floats), per wave
#define ROW_STRIDE 20                 // 16 ch + 4 pad
#define TV_F   (24 * ROW_STRIDE)      // 480
#define SLAB_F (TV_F + 16 + 48)       // 544

// ---------------------------------------------------------------------------
// A: pack (coalesced 32B W) + ray bounds + rank via ONE returning atomic pass.
// rt fuses (tid,rank) into one word (rank < 65536: avg 20 samples/tid).
// ---------------------------------------------------------------------------
__global__ __launch_bounds__(256) void pack_bounds_rank(
    const int*   __restrict__ tenso_id,
    const int*   __restrict__ ray_id,     // sorted
    const int*   __restrict__ gis, const int* __restrict__ gil,
    const float* __restrict__ gws, const float* __restrict__ gwl,
    int* __restrict__ cursor,             // zeroed; becomes counts
    int* __restrict__ rt,                 // (tid<<16)|rank
    int* __restrict__ ray_start,
    float4* __restrict__ pack)
{
    int n = blockIdx.x * 256 + threadIdx.x;
    if (n >= N_SAMP) return;
    const int lane = threadIdx.x & 63;

    const int tid = tenso_id[n];
    const int rk = atomicAdd(&cursor[tid], 1);     // the single atomic pass
    rt[n] = (tid << 16) | rk;

    unsigned bits = (unsigned)gis[n*3+0] | ((unsigned)gis[n*3+1] << 3) | ((unsigned)gis[n*3+2] << 6)
                  | ((unsigned)gil[n*3+0] << 9) | ((unsigned)gil[n*3+1] << 12) | ((unsigned)gil[n*3+2] << 15);
    float4 A = make_float4(gws[n*3+0], gws[n*3+1], gws[n*3+2], gwl[n*3+0]);
    float4 B = make_float4(gwl[n*3+1], gwl[n*3+2], __uint_as_float(bits), 0.0f);
    pack[(size_t)n * 2 + 0] = A;
    pack[(size_t)n * 2 + 1] = B;

    const int r = ray_id[n];
    const int rup = __shfl_up(r, 1);               // lane-1's ray id
    int rprev;
    if (lane == 0) rprev = (n == 0) ? -1 : ray_id[n - 1];
    else           rprev = rup;
    for (int q = rprev + 1; q <= r; ++q) ray_start[q] = n;
    if (n == N_SAMP - 1) {
        for (int q = r + 1; q <= N_RAYS; ++q) ray_start[q] = N_SAMP;
    }
}

// ---------------------------------------------------------------------------
// B+C fused: exclusive scan of counts -> starts (49 co-resident blocks, spin
// barrier), publish starts (2nd spin barrier), then the same 49 blocks
// grid-stride the perm build (8MB traffic; saves one dispatch).
// ---------------------------------------------------------------------------
__global__ __launch_bounds__(256) void scan_finalize(
    const int* __restrict__ cursor,   // counts
    const int* __restrict__ rt,       // (tid<<16)|rank
    int* __restrict__ starts,         // P_TENSO+1
    int* __restrict__ bsums,
    int* __restrict__ flag,           // [0]=barrier1, [1]=barrier2
    int* __restrict__ perm)
{
    __shared__ int lds[257];
    const int b = blockIdx.x;
    const int t = threadIdx.x;
    const int base = b * 1024 + t * 4;

    int v[4]; int s = 0;
    #pragma unroll
    for (int i = 0; i < 4; ++i) {
        int idx = base + i;
        v[i] = (idx < P_TENSO) ? cursor[idx] : 0;
        s += v[i];
    }
    lds[t] = s;
    __syncthreads();
    for (int d = 1; d < 256; d <<= 1) {
        int x = (t >= d) ? lds[t - d] : 0;
        __syncthreads();
        lds[t] += x;
        __syncthreads();
    }
    if (t == 255) bsums[b] = lds[255];

    // ---- barrier 1 across the 49 blocks (bsums published) ----
    __threadfence();
    __syncthreads();
    if (t == 0) {
        atomicAdd(&flag[0], 1);
        while (atomicAdd(&flag[0], 0) < NB_SCAN) { }
    }
    __syncthreads();
    __threadfence();

    // every block computes its global prefix = sum of bsums[0..b)
    if (t < 64) {
        int x = (t < b) ? bsums[t] : 0;
        #pragma unroll
        for (int m = 1; m < 64; m <<= 1) x += __shfl_xor(x, m);
        if (t == 0) lds[256] = x;
    }
    __syncthreads();
    const int pre = lds[256];

    int run = pre + ((t > 0) ? lds[t - 1] : 0);
    #pragma unroll
    for (int i = 0; i < 4; ++i) {
        int idx = base + i;
        if (idx < P_TENSO) starts[idx] = run;
        run += v[i];
        if (idx == P_TENSO - 1) starts[P_TENSO] = run;   // total == N_SAMP
    }

    // ---- barrier 2 across the 49 blocks (starts published) ----
    __threadfence();
    __syncthreads();
    if (t == 0) {
        atomicAdd(&flag[1], 1);
        while (atomicAdd(&flag[1], 0) < NB_SCAN) { }
    }
    __syncthreads();
    __threadfence();

    // ---- finalize: pos = starts[tid] + rank; perm[pos] = n ----
    for (int n = b * 256 + t; n < N_SAMP; n += NB_SCAN * 256) {
        const unsigned w = (unsigned)rt[n];
        perm[starts[w >> 16] + (int)(w & 0xFFFFu)] = n;   // random 4B, L2
    }
}

// ---------------------------------------------------------------------------
// Gather: persistent waves (2048 blocks x 4 waves); each wave loops tids
// t, t+8192, ... . Next tid's slab is register-staged BEFORE computing the
// current tid (HBM stage latency hides under compute+pack loads) and written
// to LDS after (same-wave DS ordering => single buffer, no barrier).
// Reads perm->pack (random 32B, line-efficient, measured-free); scatter-
// writes results to ORIGINAL n order (measured-free) so ray_render streams.
// ---------------------------------------------------------------------------
__global__ __launch_bounds__(256) void gather_phase(
    const float* __restrict__ trivecs,   // (P,16,3,8)
    const float* __restrict__ densities, // (P,16)
    const float* __restrict__ colors,    // (P,16,3)
    const int*   __restrict__ starts,    // P_TENSO+1 (cnt = diff)
    const int*   __restrict__ perm,
    const float4* __restrict__ pack,
    float* __restrict__ results_f)       // [n*4 + j], original order
{
    __shared__ __align__(16) float lds[4 * SLAB_F];
    const int lane = threadIdx.x & 63;
    const int wv   = threadIdx.x >> 6;
    float* slab = lds + wv * SLAB_F;
    float* dl   = slab + TV_F;
    float* cl   = dl + 16;
    const int g = lane >> 2;   // sample slot 0..15
    const int j = lane & 3;    // channel group

    // lane-constant LDS write indices for the 6 slab words
    int wr0,wr1,wr2,wr3,wr4,wr5;
    {
        int l, c, rem;
        l = lane;       c = l/24; rem = l - c*24; wr0 = rem*ROW_STRIDE + c;
        l = lane + 64;  c = l/24; rem = l - c*24; wr1 = rem*ROW_STRIDE + c;
        l = lane + 128; c = l/24; rem = l - c*24; wr2 = rem*ROW_STRIDE + c;
        l = lane + 192; c = l/24; rem = l - c*24; wr3 = rem*ROW_STRIDE + c;
        l = lane + 256; c = l/24; rem = l - c*24; wr4 = rem*ROW_STRIDE + c;
        l = lane + 320; c = l/24; rem = l - c*24; wr5 = rem*ROW_STRIDE + c;
    }
    int cli; { int c = lane/3, k = lane - c*3; cli = k*16 + c; }

    int t = blockIdx.x * 4 + wv;        // in [0, 8192) — always valid

    // stage tid t into registers, then LDS
    float v0,v1,v2,v3,v4,v5, vd, vc;
    {
        const float* tvg = trivecs + (size_t)t * 384;
        v0 = tvg[lane];       v1 = tvg[lane + 64];  v2 = tvg[lane + 128];
        v3 = tvg[lane + 192]; v4 = tvg[lane + 256]; v5 = tvg[lane + 320];
        vd = (lane < 16) ? densities[(size_t)t * 16 + lane] : 0.0f;
        vc = (lane < 48) ? colors[(size_t)t * 48 + lane]    : 0.0f;
    }
    int st0 = starts[t], st1 = starts[t + 1];
    slab[wr0]=v0; slab[wr1]=v1; slab[wr2]=v2; slab[wr3]=v3; slab[wr4]=v4; slab[wr5]=v5;
    if (lane < 16) dl[lane] = vd;
    if (lane < 48) cl[cli]  = vc;

    for (;;) {
        const int tn = t + NW_GATHER;
        const bool hn = (tn < P_TENSO);
        int stn0 = 0, stn1 = 0;
        if (hn) {                        // issue next tid's stage loads NOW
            const float* tvn = trivecs + (size_t)tn * 384;
            v0 = tvn[lane];       v1 = tvn[lane + 64];  v2 = tvn[lane + 128];
            v3 = tvn[lane + 192]; v4 = tvn[lane + 256]; v5 = tvn[lane + 320];
            vd = (lane < 16) ? densities[(size_t)tn * 16 + lane] : 0.0f;
            vc = (lane < 48) ? colors[(size_t)tn * 48 + lane]    : 0.0f;
            stn0 = starts[tn]; stn1 = starts[tn + 1];
        }

        // ---- compute current tid t from LDS ----
        const int start = st0, end = st1, cnt = st1 - st0;
        if (cnt > 0) {
            int p = start + g;
            int n = perm[(p < end) ? p : (end - 1)];

            const float4 dens4 = *(const float4*)(dl + 4 * j);
            const float4 col0  = *(const float4*)(cl + 4 * j);
            const float4 col1  = *(const float4*)(cl + 16 + 4 * j);
            const float4 col2  = *(const float4*)(cl + 32 + 4 * j);

            const int niter = (cnt + 15) >> 4;
            for (int it = 0; it < niter; ++it) {
                const bool valid = (p < end);
                const int sn = n;                 // saved for the store

                const float4 A = pack[(size_t)sn * 2 + 0];   // random 32B
                const float4 B = pack[(size_t)sn * 2 + 1];

                if (it + 1 < niter) {             // prefetch next trip's perm
                    p = start + (it + 1) * 16 + g;
                    n = perm[(p < end) ? p : (end - 1)];
                }

                const unsigned bits = __float_as_uint(B.z);

                float4 f;
                {
                    const int is = bits & 7, il = (bits >> 9) & 7;
                    const float4 vs = *(const float4*)(slab + is * ROW_STRIDE + 4 * j);
                    const float4 vl = *(const float4*)(slab + il * ROW_STRIDE + 4 * j);
                    f.x = vs.x * A.x + vl.x * A.w;
                    f.y = vs.y * A.x + vl.y * A.w;
                    f.z = vs.z * A.x + vl.z * A.w;
                    f.w = vs.w * A.x + vl.w * A.w;
                }
                {
                    const int is = (bits >> 3) & 7, il = (bits >> 12) & 7;
                    const float4 vs = *(const float4*)(slab + (8 + is) * ROW_STRIDE + 4 * j);
                    const float4 vl = *(const float4*)(slab + (8 + il) * ROW_STRIDE + 4 * j);
                    f.x *= vs.x * A.y + vl.x * B.x;
                    f.y *= vs.y * A.y + vl.y * B.x;
                    f.z *= vs.z * A.y + vl.z * B.x;
                    f.w *= vs.w * A.y + vl.w * B.x;
                }
                {
                    const int is = (bits >> 6) & 7, il = (bits >> 15) & 7;
                    const float4 vs = *(const float4*)(slab + (16 + is) * ROW_STRIDE + 4 * j);
                    const float4 vl = *(const float4*)(slab + (16 + il) * ROW_STRIDE + 4 * j);
                    f.x *= vs.x * A.z + vl.x * B.y;
                    f.y *= vs.y * A.z + vl.y * B.y;
                    f.z *= vs.z * A.z + vl.z * B.y;
                    f.w *= vs.w * A.z + vl.w * B.y;
                }

                float s0 = f.x * dens4.x + f.y * dens4.y + f.z * dens4.z + f.w * dens4.w;
                float s1 = f.x * col0.x  + f.y * col0.y  + f.z * col0.z  + f.w * col0.w;
                float s2 = f.x * col1.x  + f.y * col1.y  + f.z * col1.z  + f.w * col1.w;
                float s3 = f.x * col2.x  + f.y * col2.y  + f.z * col2.z  + f.w * col2.w;

                s0 += __shfl_xor(s0, 1); s0 += __shfl_xor(s0, 2);
                s1 += __shfl_xor(s1, 1); s1 += __shfl_xor(s1, 2);
                s2 += __shfl_xor(s2, 1); s2 += __shfl_xor(s2, 2);
                s3 += __shfl_xor(s3, 1); s3 += __shfl_xor(s3, 2);

                const float sj = (j == 0) ? s0 : (j == 1) ? s1 : (j == 2) ? s2 : s3;
                float val;
                if (j == 0) {
                    float dens = fmaxf(sj, 0.0f) + __logf(1.0f + __expf(-fabsf(sj)));
                    val = -(dens * DENS_SCALE) * STEP_SZ;            // lt
                } else {
                    val = 1.0f / (1.0f + __expf(-sj));               // sigmoid
                }
                if (valid) results_f[(size_t)sn * 4 + j] = val;      // scatter
            }
        }

        if (!hn) break;
        // write next tid's slab (same-wave DS ordering: reads above complete
        // in program order before these writes — no barrier needed)
        slab[wr0]=v0; slab[wr1]=v1; slab[wr2]=v2; slab[wr3]=v3; slab[wr4]=v4; slab[wr5]=v5;
        if (lane < 16) dl[lane] = vd;
        if (lane < 48) cl[cli]  = vc;
        st0 = stn0; st1 = stn1; t = tn;
    }
}

// ---------------------------------------------------------------------------
// E: 4 lanes per ray. Coalesced 64B loads per quad; quad prefix-product of
// exp(lt) via width-4 shfls (1 exp/lane/iter); ~3 iters instead of ~10.
// ---------------------------------------------------------------------------
__global__ __launch_bounds__(256) void ray_render(
    const float4* __restrict__ results,  // original n order
    const float*  __restrict__ t_min,
    const float*  __restrict__ bg,
    const int*    __restrict__ ray_start,
    const int*    __restrict__ step_id,
    float* __restrict__ out)
{
    const int lane = threadIdx.x & 63;
    const int g    = lane & 3;
    const int r    = (blockIdx.x * 256 + threadIdx.x) >> 2;
    if (r >= N_RAYS) return;
    const int s = ray_start[r];
    const int e = ray_start[r + 1];
    const float tmin_r = t_min[r];

    float eT = 1.0f, aR = 0.0f, aG = 0.0f, aB = 0.0f, aD = 0.0f;
    const int niter = (e - s + 3) >> 2;
    for (int it = 0; it < niter; ++it) {
        const int idx = s + it * 4 + g;
        const bool valid = (idx < e);
        const int ci = valid ? idx : (e - 1);
        const float4 res = results[ci];
        const float z = tmin_r + (float)step_id[ci] * STEP_SZ;
        const float elt = valid ? __expf(res.x) : 1.0f;   // exp(lt), 1 => w=0

        // exclusive prefix product of elt within the quad
        float excl = 1.0f;
        const float v1 = __shfl_up(elt, 1, 4); if (g >= 1) excl *= v1;
        const float v2 = __shfl_up(elt, 2, 4); if (g >= 2) excl *= v2;
        const float v3 = __shfl_up(elt, 3, 4); if (g >= 3) excl *= v3;

        const float w = eT * excl * (1.0f - elt);
        aR += w * res.y;
        aG += w * res.z;
        aB += w * res.w;
        aD += w * z;

        const float tot = __shfl(excl * elt, 3, 4);  // product of all 4 elts
        eT *= tot;
    }

    // quad reduction of accumulators
    aR += __shfl_xor(aR, 1); aR += __shfl_xor(aR, 2);
    aG += __shfl_xor(aG, 1); aG += __shfl_xor(aG, 2);
    aB += __shfl_xor(aB, 1); aB += __shfl_xor(aB, 2);
    aD += __shfl_xor(aD, 1); aD += __shfl_xor(aD, 2);

    const float outv = (g == 0) ? aR + eT * bg[0]
                     : (g == 1) ? aG + eT * bg[1]
                     : (g == 2) ? aB + eT * bg[2]
                     : aD;
    out[g * N_RAYS + r] = outv;
    if (g == 0) out[4 * N_RAYS + r] = 1.0f - eT;
}

// ---------------------------------------------------------------------------
// Fallback (ws too small): single fused kernel, original layouts.
// ---------------------------------------------------------------------------
__global__ __launch_bounds__(256) void trivec_render_fallback(
    const float* __restrict__ trivecs, const float* __restrict__ densities,
    const float* __restrict__ colors, const float* __restrict__ gws,
    const float* __restrict__ gwl, const float* __restrict__ t_min,
    const float* __restrict__ bg, const int* __restrict__ gis,
    const int* __restrict__ gil, const int* __restrict__ tenso_id,
    const int* __restrict__ ray_id, const int* __restrict__ step_id,
    float* __restrict__ out)
{
    const int lane = threadIdx.x & 63;
    const int r = blockIdx.x * 4 + (threadIdx.x >> 6);
    if (r >= N_RAYS) return;
    const int c = lane & 15;
    const int g = lane >> 4;
    int lo = 0, hi = N_SAMP;
    while (lo < hi) { int mid = (lo + hi) >> 1; if (ray_id[mid] < r) lo = mid + 1; else hi = mid; }
    const int seg_start = lo;
    hi = N_SAMP;
    while (lo < hi) { int mid = (lo + hi) >> 1; if (ray_id[mid] < r + 1) lo = mid + 1; else hi = mid; }
    const int seg_end = lo;
    const float tmin_r = t_min[r];
    float Tlog = 0.0f, accR = 0.0f, accG = 0.0f, accB = 0.0f, accD = 0.0f;
    const int niter = (seg_end - seg_start + 3) >> 2;
    for (int it = 0; it < niter; ++it) {
        const int n = seg_start + it * 4 + g;
        const bool valid = (n < seg_end);
        const int nc = valid ? n : (seg_end - 1);
        const int tid = tenso_id[nc];
        const float* tv = trivecs + (size_t)tid * 384 + c * 24;
        float f = 1.0f;
        #pragma unroll
        for (int a = 0; a < 3; ++a) {
            const int is = gis[nc*3+a], il = gil[nc*3+a];
            const float wS = gws[nc*3+a], wL = gwl[nc*3+a];
            f *= (tv[a*8+is] * wS + tv[a*8+il] * wL);
        }
        const float dns = densities[(size_t)tid * 16 + c];
        const float* colp = colors + ((size_t)tid * 16 + c) * 3;
        float s0 = f*dns, s1 = f*colp[0], s2 = f*colp[1], s3 = f*colp[2];
        #pragma unroll
        for (int m = 1; m < 16; m <<= 1) {
            s0 += __shfl_xor(s0, m); s1 += __shfl_xor(s1, m);
            s2 += __shfl_xor(s2, m); s3 += __shfl_xor(s3, m);
        }
        float dens = fmaxf(s0, 0.0f) + __logf(1.0f + __expf(-fabsf(s0)));
        const float lt = valid ? (-dens * STEP_SZ) : 0.0f;
        const float alpha = 1.0f - __expf(lt);
        const float rr = 1.0f/(1.0f+__expf(-s1)), gg = 1.0f/(1.0f+__expf(-s2)), bb = 1.0f/(1.0f+__expf(-s3));
        const float z = tmin_r + (float)step_id[nc] * STEP_SZ;
        const float lt0 = __shfl(lt,0), lt1 = __shfl(lt,16), lt2 = __shfl(lt,32), lt3 = __shfl(lt,48);
        float excl = Tlog;
        if (g > 0) excl += lt0;
        if (g > 1) excl += lt1;
        if (g > 2) excl += lt2;
        const float w = alpha * __expf(excl);
        Tlog += lt0 + lt1 + lt2 + lt3;
        accR += w*rr; accG += w*gg; accB += w*bb; accD += w*z;
    }
    accR += __shfl_xor(accR,16); accR += __shfl_xor(accR,32);
    accG += __shfl_xor(accG,16); accG += __shfl_xor(accG,32);
    accB += __shfl_xor(accB,16); accB += __shfl_xor(accB,32);
    accD += __shfl_xor(accD,16); accD += __shfl_xor(accD,32);
    const float bgw = __expf(Tlog);
    if (lane == 0) {
        out[0*N_RAYS+r] = accR + bgw*bg[0];
        out[1*N_RAYS+r] = accG + bgw*bg[1];
        out[2*N_RAYS+r] = accB + bgw*bg[2];
        out[3*N_RAYS+r] = accD;
        out[4*N_RAYS+r] = 1.0f - bgw;
    }
}

extern "C" void kernel_launch(void* const* d_in, const int* in_sizes, int n_in,
                              void* d_out, int out_size, void* d_ws, size_t ws_size,
                              hipStream_t stream) {
    const float* trivecs   = (const float*)d_in[0];
    const float* densities = (const float*)d_in[1];
    const float* colors    = (const float*)d_in[2];
    const float* gws       = (const float*)d_in[3];
    const float* gwl       = (const float*)d_in[4];
    const float* t_min     = (const float*)d_in[5];
    const float* bg        = (const float*)d_in[6];
    const int*   gis       = (const int*)d_in[7];
    const int*   gil       = (const int*)d_in[8];
    const int*   tenso_id  = (const int*)d_in[9];
    const int*   ray_id    = (const int*)d_in[10];
    const int*   step_id   = (const int*)d_in[11];
    float* out = (float*)d_out;

    if (ws_size < (size_t)WS_NEED) {
        trivec_render_fallback<<<(N_RAYS + 3) / 4, 256, 0, stream>>>(
            trivecs, densities, colors, gws, gwl, t_min, bg,
            gis, gil, tenso_id, ray_id, step_id, out);
        return;
    }

    char* ws = (char*)d_ws;
    float4* pack     = (float4*)(ws + OFF_PACK);
    float4* results  = (float4*)(ws + OFF_RESULTS);
    int*    perm     = (int*)(ws + OFF_PERM);
    int*    rt       = (int*)(ws + OFF_RT);
    int*    cursor   = (int*)(ws + OFF_CURSOR);
    int*    starts   = (int*)(ws + OFF_STARTS);
    int*    bsums    = (int*)(ws + OFF_BSUMS);
    int*    flag     = (int*)(ws + OFF_FLAG);
    int*    raystart = (int*)(ws + OFF_RSTART);

    // zero cursor + starts + bsums + flags in one async memset
    hipMemsetAsync(ws + OFF_CURSOR, 0, (OFF_FLAG + 64) - OFF_CURSOR, stream);

    pack_bounds_rank<<<(N_SAMP + 255) / 256, 256, 0, stream>>>(
        tenso_id, ray_id, gis, gil, gws, gwl, cursor, rt, raystart, pack);
    scan_finalize<<<NB_SCAN, 256, 0, stream>>>(
        cursor, rt, starts, bsums, flag, perm);
    gather_phase<<<NB_GATHER, 256, 0, stream>>>(
        trivecs, densities, colors, starts, perm, pack, (float*)results);
    ray_render<<<(N_RAYS * 4 + 255) / 256, 256, 0, stream>>>(
        results, t_min, bg, raystart, step_id, out);
}

// Round 6
// 275.166 us; speedup vs baseline: 1.1575x; 1.1575x over previous
//
#include <hip/hip_runtime.h>
#include <math.h>

#define HN       250
#define WN       400
#define N_RAYS   (HN * WN)        // 100000
#define N_SAMP   1000000
#define P_TENSO  50000
#define STEP_SZ  0.005f
#define DENS_SCALE 1.0f           // min(1/(1-0), 25) = 1
#define NB_SCAN  ((P_TENSO + 1023) / 1024)   // 49

// NOTE (R7): cooperative grid.sync() ~100 us/sync on MI355X — don't re-fuse.
// NOTE (R8): each returning atomicAdd costs a 64B line transaction.
// NOTE (R9/R10): gather is LATENCY-bound; 32B-packed random loads and scatter
// stores are free INSIDE gather; scattered partial-line stores in a thin
// kernel cost 2-4x traffic (RMW).
// NOTE (R11): random loads are only free when LINE-EFFICIENT (packed 32B).
// NOTE (R12): pipeline pinned ~278us: gather 62, others <61.
// NOTE (R13): persistent-wave gather REGRESSED (72us, occ 39%): holding next
// tid's stage in regs serializes; 49-block merged finalize too narrow. Also:
// ~38 dispatches/iteration (only 5 ours) => ~100us harness overhead floor.
// NOTE (R14): R10's failure was 2 samples/quad (2 chains/lane, +VGPR); this
// round: 2 lanes/sample x 8 ch/lane = 32 samples/trip, ONE chain per lane.

// ---------------- workspace layout (bytes) ----------------
#define OFF_PACK    0            // 1M x 32B sample structs, original (n) order
#define OFF_RESULTS 32000000     // 1M x 16B (lt,r,g,b), ORIGINAL (n) order
#define OFF_PERM    48000000     // 1M int, pos -> n
#define OFF_RT      52000000     // 1M int, (tid<<16)|rank
#define OFF_CURSOR  56000000     // 50K int (atomic counters == final counts)
#define OFF_STARTS  56200000     // 50K int
#define OFF_BSUMS   56400000     // 64 int
#define OFF_FLAG    56400512     // 1 int (spin-barrier arrival)
#define OFF_RSTART  56401024     // (N_RAYS+1) int
#define WS_NEED     (56401024 + 400004 + 64)

// gather slab layout (floats), per wave
#define ROW_STRIDE 20                 // 16 ch + 4 pad
#define TV_F   (24 * ROW_STRIDE)      // 480
#define SLAB_F (TV_F + 16 + 48)       // 544

// ---------------------------------------------------------------------------
// A: pack (coalesced 32B W) + ray bounds + rank via ONE returning atomic pass.
// rt fuses (tid,rank) into one word (rank < 65536: avg 20 samples/tid).
// ---------------------------------------------------------------------------
__global__ __launch_bounds__(256) void pack_bounds_rank(
    const int*   __restrict__ tenso_id,
    const int*   __restrict__ ray_id,     // sorted
    const int*   __restrict__ gis, const int* __restrict__ gil,
    const float* __restrict__ gws, const float* __restrict__ gwl,
    int* __restrict__ cursor,             // zeroed; becomes counts
    int* __restrict__ rt,                 // (tid<<16)|rank
    int* __restrict__ ray_start,
    float4* __restrict__ pack)
{
    int n = blockIdx.x * 256 + threadIdx.x;
    if (n >= N_SAMP) return;
    const int lane = threadIdx.x & 63;

    const int tid = tenso_id[n];
    const int rk = atomicAdd(&cursor[tid], 1);     // the single atomic pass
    rt[n] = (tid << 16) | rk;

    unsigned bits = (unsigned)gis[n*3+0] | ((unsigned)gis[n*3+1] << 3) | ((unsigned)gis[n*3+2] << 6)
                  | ((unsigned)gil[n*3+0] << 9) | ((unsigned)gil[n*3+1] << 12) | ((unsigned)gil[n*3+2] << 15);
    float4 A = make_float4(gws[n*3+0], gws[n*3+1], gws[n*3+2], gwl[n*3+0]);
    float4 B = make_float4(gwl[n*3+1], gwl[n*3+2], __uint_as_float(bits), 0.0f);
    pack[(size_t)n * 2 + 0] = A;
    pack[(size_t)n * 2 + 1] = B;

    const int r = ray_id[n];
    const int rup = __shfl_up(r, 1);               // lane-1's ray id
    int rprev;
    if (lane == 0) rprev = (n == 0) ? -1 : ray_id[n - 1];
    else           rprev = rup;
    for (int q = rprev + 1; q <= r; ++q) ray_start[q] = n;
    if (n == N_SAMP - 1) {
        for (int q = r + 1; q <= N_RAYS; ++q) ray_start[q] = N_SAMP;
    }
}

// ---------------------------------------------------------------------------
// B: fused exclusive scan of counts -> starts. 49 blocks (co-resident on 256
// CUs), internal spin barrier on an arrival counter.
// ---------------------------------------------------------------------------
__global__ __launch_bounds__(256) void scan_fused(
    const int* __restrict__ cursor,   // counts
    int* __restrict__ starts,
    int* __restrict__ bsums,
    int* __restrict__ flag)
{
    __shared__ int lds[257];
    const int b = blockIdx.x;
    const int t = threadIdx.x;
    const int base = b * 1024 + t * 4;

    int v[4]; int s = 0;
    #pragma unroll
    for (int i = 0; i < 4; ++i) {
        int idx = base + i;
        v[i] = (idx < P_TENSO) ? cursor[idx] : 0;
        s += v[i];
    }
    lds[t] = s;
    __syncthreads();
    for (int d = 1; d < 256; d <<= 1) {
        int x = (t >= d) ? lds[t - d] : 0;
        __syncthreads();
        lds[t] += x;
        __syncthreads();
    }
    if (t == 255) bsums[b] = lds[255];

    // ---- barrier across the 49 blocks ----
    __threadfence();
    __syncthreads();
    if (t == 0) {
        atomicAdd(flag, 1);
        while (atomicAdd(flag, 0) < gridDim.x) { }
    }
    __syncthreads();
    __threadfence();

    // every block computes its global prefix = sum of bsums[0..b)
    if (t < 64) {
        int x = (t < b) ? bsums[t] : 0;
        #pragma unroll
        for (int m = 1; m < 64; m <<= 1) x += __shfl_xor(x, m);
        if (t == 0) lds[256] = x;
    }
    __syncthreads();
    const int pre = lds[256];

    int run = pre + ((t > 0) ? lds[t - 1] : 0);
    #pragma unroll
    for (int i = 0; i < 4; ++i) {
        int idx = base + i;
        if (idx < P_TENSO) starts[idx] = run;
        run += v[i];
    }
}

// ---------------------------------------------------------------------------
// C: positions without atomics: pos = starts[tid] + rank. Reads only rt (4MB).
// ---------------------------------------------------------------------------
__global__ __launch_bounds__(256) void finalize_perm(
    const int* __restrict__ rt,
    const int* __restrict__ starts,
    int* __restrict__ perm)
{
    int n = blockIdx.x * 256 + threadIdx.x;
    if (n >= N_SAMP) return;
    const unsigned w = (unsigned)rt[n];
    int pos = starts[w >> 16] + (int)(w & 0xFFFFu);
    perm[pos] = n;           // random 4B into 4MB (L2-resident)
}

// ---------------------------------------------------------------------------
// Gather: one wave per tensoRF id; lanes = 32 samples x 2 channel-halves.
// R14: 2 lanes/sample, 8 channels/lane -> 32 samples/trip. ~90% of tids
// (cnt<=32, Poisson mean 20) finish in ONE trip: per-wave serial dependent
// chain halves vs 16/trip, with ONE sample chain per lane (R10's failure
// mode was two). Cross-pair reduce = single shfl_xor(s,1); pairwise float2
// stores keep the 16B result granule. perm prefetch one trip ahead.
// ---------------------------------------------------------------------------
__global__ __launch_bounds__(256) void gather_phase(
    const float* __restrict__ trivecs,   // (P,16,3,8)
    const float* __restrict__ densities, // (P,16)
    const float* __restrict__ colors,    // (P,16,3)
    const int*   __restrict__ starts,
    const int*   __restrict__ counts,    // == cursor
    const int*   __restrict__ perm,
    const float4* __restrict__ pack,
    float* __restrict__ results_f)       // [n*4 + j], original order
{
    __shared__ __align__(16) float lds[4 * SLAB_F];
    const int lane = threadIdx.x & 63;
    const int wv   = threadIdx.x >> 6;
    const int t    = blockIdx.x * 4 + wv;
    if (t >= P_TENSO) return;

    const int start = starts[t];
    const int cnt   = counts[t];
    if (cnt == 0) return;

    float* slab = lds + wv * SLAB_F;
    float* dl   = slab + TV_F;
    float* cl   = dl + 16;

    const int pr = lane >> 1;   // sample slot 0..31
    const int h  = lane & 1;    // channel half (0: ch 0-7, 1: ch 8-15)
    const int hc = h * 8;       // channel base
    const int end = start + cnt;

    // trip-0 perm load issued before staging (flies under the slab loads)
    int p = start + pr;
    int n = perm[(p < end) ? p : (end - 1)];

    const float* tvg = trivecs + (size_t)t * 384;
    #pragma unroll
    for (int i = 0; i < 6; ++i) {
        int l = lane + i * 64;
        int c = l / 24;
        int rem = l - c * 24;
        slab[rem * ROW_STRIDE + c] = tvg[l];
    }
    if (lane < 16) dl[lane] = densities[(size_t)t * 16 + lane];
    if (lane < 48) {
        int c = lane / 3, k = lane - c * 3;
        cl[k * 16 + c] = colors[(size_t)t * 48 + lane];
    }

    // loop-invariant 8-channel slices (this lane's half)
    const float4 dnA = *(const float4*)(dl + hc);
    const float4 dnB = *(const float4*)(dl + hc + 4);
    const float4 c0A = *(const float4*)(cl + hc);
    const float4 c0B = *(const float4*)(cl + hc + 4);
    const float4 c1A = *(const float4*)(cl + 16 + hc);
    const float4 c1B = *(const float4*)(cl + 16 + hc + 4);
    const float4 c2A = *(const float4*)(cl + 32 + hc);
    const float4 c2B = *(const float4*)(cl + 32 + hc + 4);

    const int niter = (cnt + 31) >> 5;   // 32 samples per trip

    for (int it = 0; it < niter; ++it) {
        const bool valid = (p < end);
        const int sn = n;                 // saved for the store

        const float4 A = pack[(size_t)sn * 2 + 0];   // random 32B, pair-bcast
        const float4 B = pack[(size_t)sn * 2 + 1];

        if (it + 1 < niter) {             // prefetch next trip's perm
            p = start + (it + 1) * 32 + pr;
            n = perm[(p < end) ? p : (end - 1)];
        }

        const unsigned bits = __float_as_uint(B.z);

        float4 fA, fB;
        {
            const int is = bits & 7, il = (bits >> 9) & 7;
            const float4 vsA = *(const float4*)(slab + is * ROW_STRIDE + hc);
            const float4 vsB = *(const float4*)(slab + is * ROW_STRIDE + hc + 4);
            const float4 vlA = *(const float4*)(slab + il * ROW_STRIDE + hc);
            const float4 vlB = *(const float4*)(slab + il * ROW_STRIDE + hc + 4);
            fA.x = vsA.x * A.x + vlA.x * A.w;
            fA.y = vsA.y * A.x + vlA.y * A.w;
            fA.z = vsA.z * A.x + vlA.z * A.w;
            fA.w = vsA.w * A.x + vlA.w * A.w;
            fB.x = vsB.x * A.x + vlB.x * A.w;
            fB.y = vsB.y * A.x + vlB.y * A.w;
            fB.z = vsB.z * A.x + vlB.z * A.w;
            fB.w = vsB.w * A.x + vlB.w * A.w;
        }
        {
            const int is = (bits >> 3) & 7, il = (bits >> 12) & 7;
            const float4 vsA = *(const float4*)(slab + (8 + is) * ROW_STRIDE + hc);
            const float4 vsB = *(const float4*)(slab + (8 + is) * ROW_STRIDE + hc + 4);
            const float4 vlA = *(const float4*)(slab + (8 + il) * ROW_STRIDE + hc);
            const float4 vlB = *(const float4*)(slab + (8 + il) * ROW_STRIDE + hc + 4);
            fA.x *= vsA.x * A.y + vlA.x * B.x;
            fA.y *= vsA.y * A.y + vlA.y * B.x;
            fA.z *= vsA.z * A.y + vlA.z * B.x;
            fA.w *= vsA.w * A.y + vlA.w * B.x;
            fB.x *= vsB.x * A.y + vlB.x * B.x;
            fB.y *= vsB.y * A.y + vlB.y * B.x;
            fB.z *= vsB.z * A.y + vlB.z * B.x;
            fB.w *= vsB.w * A.y + vlB.w * B.x;
        }
        {
            const int is = (bits >> 6) & 7, il = (bits >> 15) & 7;
            const float4 vsA = *(const float4*)(slab + (16 + is) * ROW_STRIDE + hc);
            const float4 vsB = *(const float4*)(slab + (16 + is) * ROW_STRIDE + hc + 4);
            const float4 vlA = *(const float4*)(slab + (16 + il) * ROW_STRIDE + hc);
            const float4 vlB = *(const float4*)(slab + (16 + il) * ROW_STRIDE + hc + 4);
            fA.x *= vsA.x * A.z + vlA.x * B.y;
            fA.y *= vsA.y * A.z + vlA.y * B.y;
            fA.z *= vsA.z * A.z + vlA.z * B.y;
            fA.w *= vsA.w * A.z + vlA.w * B.y;
            fB.x *= vsB.x * A.z + vlB.x * B.y;
            fB.y *= vsB.y * A.z + vlB.y * B.y;
            fB.z *= vsB.z * A.z + vlB.z * B.y;
            fB.w *= vsB.w * A.z + vlB.w * B.y;
        }

        float s0 = fA.x*dnA.x + fA.y*dnA.y + fA.z*dnA.z + fA.w*dnA.w
                 + fB.x*dnB.x + fB.y*dnB.y + fB.z*dnB.z + fB.w*dnB.w;
        float s1 = fA.x*c0A.x + fA.y*c0A.y + fA.z*c0A.z + fA.w*c0A.w
                 + fB.x*c0B.x + fB.y*c0B.y + fB.z*c0B.z + fB.w*c0B.w;
        float s2 = fA.x*c1A.x + fA.y*c1A.y + fA.z*c1A.z + fA.w*c1A.w
                 + fB.x*c1B.x + fB.y*c1B.y + fB.z*c1B.z + fB.w*c1B.w;
        float s3 = fA.x*c2A.x + fA.y*c2A.y + fA.z*c2A.z + fA.w*c2A.w
                 + fB.x*c2B.x + fB.y*c2B.y + fB.z*c2B.z + fB.w*c2B.w;

        // cross-pair completion: one xor step
        s0 += __shfl_xor(s0, 1);
        s1 += __shfl_xor(s1, 1);
        s2 += __shfl_xor(s2, 1);
        s3 += __shfl_xor(s3, 1);

        float2 val;
        if (h == 0) {
            float dens = fmaxf(s0, 0.0f) + __logf(1.0f + __expf(-fabsf(s0)));
            val.x = -(dens * DENS_SCALE) * STEP_SZ;          // lt
            val.y = 1.0f / (1.0f + __expf(-s1));             // r
        } else {
            val.x = 1.0f / (1.0f + __expf(-s2));             // g
            val.y = 1.0f / (1.0f + __expf(-s3));             // b
        }
        if (valid) *(float2*)(results_f + (size_t)sn * 4 + 2 * h) = val;
    }
}

// ---------------------------------------------------------------------------
// E: 4 lanes per ray. Coalesced 64B loads per quad; quad prefix-product of
// exp(lt) via width-4 shfls (1 exp/lane/iter); ~3 iters instead of ~10.
// ---------------------------------------------------------------------------
__global__ __launch_bounds__(256) void ray_render(
    const float4* __restrict__ results,  // original n order
    const float*  __restrict__ t_min,
    const float*  __restrict__ bg,
    const int*    __restrict__ ray_start,
    const int*    __restrict__ step_id,
    float* __restrict__ out)
{
    const int lane = threadIdx.x & 63;
    const int g    = lane & 3;
    const int r    = (blockIdx.x * 256 + threadIdx.x) >> 2;
    if (r >= N_RAYS) return;
    const int s = ray_start[r];
    const int e = ray_start[r + 1];
    const float tmin_r = t_min[r];

    float eT = 1.0f, aR = 0.0f, aG = 0.0f, aB = 0.0f, aD = 0.0f;
    const int niter = (e - s + 3) >> 2;
    for (int it = 0; it < niter; ++it) {
        const int idx = s + it * 4 + g;
        const bool valid = (idx < e);
        const int ci = valid ? idx : (e - 1);
        const float4 res = results[ci];
        const float z = tmin_r + (float)step_id[ci] * STEP_SZ;
        const float elt = valid ? __expf(res.x) : 1.0f;   // exp(lt), 1 => w=0

        // exclusive prefix product of elt within the quad
        float excl = 1.0f;
        const float v1 = __shfl_up(elt, 1, 4); if (g >= 1) excl *= v1;
        const float v2 = __shfl_up(elt, 2, 4); if (g >= 2) excl *= v2;
        const float v3 = __shfl_up(elt, 3, 4); if (g >= 3) excl *= v3;

        const float w = eT * excl * (1.0f - elt);
        aR += w * res.y;
        aG += w * res.z;
        aB += w * res.w;
        aD += w * z;

        const float tot = __shfl(excl * elt, 3, 4);  // product of all 4 elts
        eT *= tot;
    }

    // quad reduction of accumulators
    aR += __shfl_xor(aR, 1); aR += __shfl_xor(aR, 2);
    aG += __shfl_xor(aG, 1); aG += __shfl_xor(aG, 2);
    aB += __shfl_xor(aB, 1); aB += __shfl_xor(aB, 2);
    aD += __shfl_xor(aD, 1); aD += __shfl_xor(aD, 2);

    const float outv = (g == 0) ? aR + eT * bg[0]
                     : (g == 1) ? aG + eT * bg[1]
                     : (g == 2) ? aB + eT * bg[2]
                     : aD;
    out[g * N_RAYS + r] = outv;
    if (g == 0) out[4 * N_RAYS + r] = 1.0f - eT;
}

// ---------------------------------------------------------------------------
// Fallback (ws too small): single fused kernel, original layouts.
// ---------------------------------------------------------------------------
__global__ __launch_bounds__(256) void trivec_render_fallback(
    const float* __restrict__ trivecs, const float* __restrict__ densities,
    const float* __restrict__ colors, const float* __restrict__ gws,
    const float* __restrict__ gwl, const float* __restrict__ t_min,
    const float* __restrict__ bg, const int* __restrict__ gis,
    const int* __restrict__ gil, const int* __restrict__ tenso_id,
    const int* __restrict__ ray_id, const int* __restrict__ step_id,
    float* __restrict__ out)
{
    const int lane = threadIdx.x & 63;
    const int r = blockIdx.x * 4 + (threadIdx.x >> 6);
    if (r >= N_RAYS) return;
    const int c = lane & 15;
    const int g = lane >> 4;
    int lo = 0, hi = N_SAMP;
    while (lo < hi) { int mid = (lo + hi) >> 1; if (ray_id[mid] < r) lo = mid + 1; else hi = mid; }
    const int seg_start = lo;
    hi = N_SAMP;
    while (lo < hi) { int mid = (lo + hi) >> 1; if (ray_id[mid] < r + 1) lo = mid + 1; else hi = mid; }
    const int seg_end = lo;
    const float tmin_r = t_min[r];
    float Tlog = 0.0f, accR = 0.0f, accG = 0.0f, accB = 0.0f, accD = 0.0f;
    const int niter = (seg_end - seg_start + 3) >> 2;
    for (int it = 0; it < niter; ++it) {
        const int n = seg_start + it * 4 + g;
        const bool valid = (n < seg_end);
        const int nc = valid ? n : (seg_end - 1);
        const int tid = tenso_id[nc];
        const float* tv = trivecs + (size_t)tid * 384 + c * 24;
        float f = 1.0f;
        #pragma unroll
        for (int a = 0; a < 3; ++a) {
            const int is = gis[nc*3+a], il = gil[nc*3+a];
            const float wS = gws[nc*3+a], wL = gwl[nc*3+a];
            f *= (tv[a*8+is] * wS + tv[a*8+il] * wL);
        }
        const float dns = densities[(size_t)tid * 16 + c];
        const float* colp = colors + ((size_t)tid * 16 + c) * 3;
        float s0 = f*dns, s1 = f*colp[0], s2 = f*colp[1], s3 = f*colp[2];
        #pragma unroll
        for (int m = 1; m < 16; m <<= 1) {
            s0 += __shfl_xor(s0, m); s1 += __shfl_xor(s1, m);
            s2 += __shfl_xor(s2, m); s3 += __shfl_xor(s3, m);
        }
        float dens = fmaxf(s0, 0.0f) + __logf(1.0f + __expf(-fabsf(s0)));
        const float lt = valid ? (-dens * STEP_SZ) : 0.0f;
        const float alpha = 1.0f - __expf(lt);
        const float rr = 1.0f/(1.0f+__expf(-s1)), gg = 1.0f/(1.0f+__expf(-s2)), bb = 1.0f/(1.0f+__expf(-s3));
        const float z = tmin_r + (float)step_id[nc] * STEP_SZ;
        const float lt0 = __shfl(lt,0), lt1 = __shfl(lt,16), lt2 = __shfl(lt,32), lt3 = __shfl(lt,48);
        float excl = Tlog;
        if (g > 0) excl += lt0;
        if (g > 1) excl += lt1;
        if (g > 2) excl += lt2;
        const float w = alpha * __expf(excl);
        Tlog += lt0 + lt1 + lt2 + lt3;
        accR += w*rr; accG += w*gg; accB += w*bb; accD += w*z;
    }
    accR += __shfl_xor(accR,16); accR += __shfl_xor(accR,32);
    accG += __shfl_xor(accG,16); accG += __shfl_xor(accG,32);
    accB += __shfl_xor(accB,16); accB += __shfl_xor(accB,32);
    accD += __shfl_xor(accD,16); accD += __shfl_xor(accD,32);
    const float bgw = __expf(Tlog);
    if (lane == 0) {
        out[0*N_RAYS+r] = accR + bgw*bg[0];
        out[1*N_RAYS+r] = accG + bgw*bg[1];
        out[2*N_RAYS+r] = accB + bgw*bg[2];
        out[3*N_RAYS+r] = accD;
        out[4*N_RAYS+r] = 1.0f - bgw;
    }
}

extern "C" void kernel_launch(void* const* d_in, const int* in_sizes, int n_in,
                              void* d_out, int out_size, void* d_ws, size_t ws_size,
                              hipStream_t stream) {
    const float* trivecs   = (const float*)d_in[0];
    const float* densities = (const float*)d_in[1];
    const float* colors    = (const float*)d_in[2];
    const float* gws       = (const float*)d_in[3];
    const float* gwl       = (const float*)d_in[4];
    const float* t_min     = (const float*)d_in[5];
    const float* bg        = (const float*)d_in[6];
    const int*   gis       = (const int*)d_in[7];
    const int*   gil       = (const int*)d_in[8];
    const int*   tenso_id  = (const int*)d_in[9];
    const int*   ray_id    = (const int*)d_in[10];
    const int*   step_id   = (const int*)d_in[11];
    float* out = (float*)d_out;

    if (ws_size < (size_t)WS_NEED) {
        trivec_render_fallback<<<(N_RAYS + 3) / 4, 256, 0, stream>>>(
            trivecs, densities, colors, gws, gwl, t_min, bg,
            gis, gil, tenso_id, ray_id, step_id, out);
        return;
    }

    char* ws = (char*)d_ws;
    float4* pack     = (float4*)(ws + OFF_PACK);
    float4* results  = (float4*)(ws + OFF_RESULTS);
    int*    perm     = (int*)(ws + OFF_PERM);
    int*    rt       = (int*)(ws + OFF_RT);
    int*    cursor   = (int*)(ws + OFF_CURSOR);
    int*    starts   = (int*)(ws + OFF_STARTS);
    int*    bsums    = (int*)(ws + OFF_BSUMS);
    int*    flag     = (int*)(ws + OFF_FLAG);
    int*    raystart = (int*)(ws + OFF_RSTART);

    // zero cursor + starts + bsums + flag in one async memset
    hipMemsetAsync(ws + OFF_CURSOR, 0, (OFF_FLAG + 64) - OFF_CURSOR, stream);

    pack_bounds_rank<<<(N_SAMP + 255) / 256, 256, 0, stream>>>(
        tenso_id, ray_id, gis, gil, gws, gwl, cursor, rt, raystart, pack);
    scan_fused<<<NB_SCAN, 256, 0, stream>>>(cursor, starts, bsums, flag);
    finalize_perm<<<(N_SAMP + 255) / 256, 256, 0, stream>>>(
        rt, starts, perm);
    gather_phase<<<(P_TENSO + 3) / 4, 256, 0, stream>>>(
        trivecs, densities, colors, starts, cursor, perm, pack, (float*)results);
    ray_render<<<(N_RAYS * 4 + 255) / 256, 256, 0, stream>>>(
        results, t_min, bg, raystart, step_id, out);
}

// Round 7
// 274.997 us; speedup vs baseline: 1.1583x; 1.0006x over previous
//
#include <hip/hip_runtime.h>
#include <math.h>

#define HN       250
#define WN       400
#define N_RAYS   (HN * WN)        // 100000
#define N_SAMP   1000000
#define P_TENSO  50000
#define STEP_SZ  0.005f
#define DENS_SCALE 1.0f           // min(1/(1-0), 25) = 1
#define NB_SCAN  ((P_TENSO + 1023) / 1024)   // 49

// NOTE (R7): cooperative grid.sync() ~100 us/sync on MI355X — don't re-fuse.
// NOTE (R8): each returning atomicAdd costs a 64B line transaction.
// NOTE (R9/R10): gather is LATENCY-bound; 32B-packed random loads and scatter
// stores are free INSIDE gather; scattered partial-line stores in a thin
// kernel cost 2-4x traffic (RMW).
// NOTE (R11): random loads are only free when LINE-EFFICIENT (packed 32B).
// NOTE (R12): pipeline pinned ~278us: gather 62, others <61.
// NOTE (R13): persistent-wave gather REGRESSED (72us, occ 39%): holding next
// tid's stage in regs serializes. ~38 dispatches/iter (only 6 ours) => ~100us
// harness overhead floor.
// NOTE (R14): 2 lanes/sample x 8ch/lane (32 samples/trip) = new best 275us,
// gather 60, but occupancy 70->52%: 4-wave blocks retire on the SLOWEST tid
// (trips bimodal 1-or-2). R15: 128-thread blocks (2 tids/block) halve the
// tail-idle; no other changes.

// ---------------- workspace layout (bytes) ----------------
#define OFF_PACK    0            // 1M x 32B sample structs, original (n) order
#define OFF_RESULTS 32000000     // 1M x 16B (lt,r,g,b), ORIGINAL (n) order
#define OFF_PERM    48000000     // 1M int, pos -> n
#define OFF_RT      52000000     // 1M int, (tid<<16)|rank
#define OFF_CURSOR  56000000     // 50K int (atomic counters == final counts)
#define OFF_STARTS  56200000     // 50K int
#define OFF_BSUMS   56400000     // 64 int
#define OFF_FLAG    56400512     // 1 int (spin-barrier arrival)
#define OFF_RSTART  56401024     // (N_RAYS+1) int
#define WS_NEED     (56401024 + 400004 + 64)

// gather slab layout (floats), per wave
#define ROW_STRIDE 20                 // 16 ch + 4 pad
#define TV_F   (24 * ROW_STRIDE)      // 480
#define SLAB_F (TV_F + 16 + 48)       // 544

// ---------------------------------------------------------------------------
// A: pack (coalesced 32B W) + ray bounds + rank via ONE returning atomic pass.
// rt fuses (tid,rank) into one word (rank < 65536: avg 20 samples/tid).
// ---------------------------------------------------------------------------
__global__ __launch_bounds__(256) void pack_bounds_rank(
    const int*   __restrict__ tenso_id,
    const int*   __restrict__ ray_id,     // sorted
    const int*   __restrict__ gis, const int* __restrict__ gil,
    const float* __restrict__ gws, const float* __restrict__ gwl,
    int* __restrict__ cursor,             // zeroed; becomes counts
    int* __restrict__ rt,                 // (tid<<16)|rank
    int* __restrict__ ray_start,
    float4* __restrict__ pack)
{
    int n = blockIdx.x * 256 + threadIdx.x;
    if (n >= N_SAMP) return;
    const int lane = threadIdx.x & 63;

    const int tid = tenso_id[n];
    const int rk = atomicAdd(&cursor[tid], 1);     // the single atomic pass
    rt[n] = (tid << 16) | rk;

    unsigned bits = (unsigned)gis[n*3+0] | ((unsigned)gis[n*3+1] << 3) | ((unsigned)gis[n*3+2] << 6)
                  | ((unsigned)gil[n*3+0] << 9) | ((unsigned)gil[n*3+1] << 12) | ((unsigned)gil[n*3+2] << 15);
    float4 A = make_float4(gws[n*3+0], gws[n*3+1], gws[n*3+2], gwl[n*3+0]);
    float4 B = make_float4(gwl[n*3+1], gwl[n*3+2], __uint_as_float(bits), 0.0f);
    pack[(size_t)n * 2 + 0] = A;
    pack[(size_t)n * 2 + 1] = B;

    const int r = ray_id[n];
    const int rup = __shfl_up(r, 1);               // lane-1's ray id
    int rprev;
    if (lane == 0) rprev = (n == 0) ? -1 : ray_id[n - 1];
    else           rprev = rup;
    for (int q = rprev + 1; q <= r; ++q) ray_start[q] = n;
    if (n == N_SAMP - 1) {
        for (int q = r + 1; q <= N_RAYS; ++q) ray_start[q] = N_SAMP;
    }
}

// ---------------------------------------------------------------------------
// B: fused exclusive scan of counts -> starts. 49 blocks (co-resident on 256
// CUs), internal spin barrier on an arrival counter.
// ---------------------------------------------------------------------------
__global__ __launch_bounds__(256) void scan_fused(
    const int* __restrict__ cursor,   // counts
    int* __restrict__ starts,
    int* __restrict__ bsums,
    int* __restrict__ flag)
{
    __shared__ int lds[257];
    const int b = blockIdx.x;
    const int t = threadIdx.x;
    const int base = b * 1024 + t * 4;

    int v[4]; int s = 0;
    #pragma unroll
    for (int i = 0; i < 4; ++i) {
        int idx = base + i;
        v[i] = (idx < P_TENSO) ? cursor[idx] : 0;
        s += v[i];
    }
    lds[t] = s;
    __syncthreads();
    for (int d = 1; d < 256; d <<= 1) {
        int x = (t >= d) ? lds[t - d] : 0;
        __syncthreads();
        lds[t] += x;
        __syncthreads();
    }
    if (t == 255) bsums[b] = lds[255];

    // ---- barrier across the 49 blocks ----
    __threadfence();
    __syncthreads();
    if (t == 0) {
        atomicAdd(flag, 1);
        while (atomicAdd(flag, 0) < gridDim.x) { }
    }
    __syncthreads();
    __threadfence();

    // every block computes its global prefix = sum of bsums[0..b)
    if (t < 64) {
        int x = (t < b) ? bsums[t] : 0;
        #pragma unroll
        for (int m = 1; m < 64; m <<= 1) x += __shfl_xor(x, m);
        if (t == 0) lds[256] = x;
    }
    __syncthreads();
    const int pre = lds[256];

    int run = pre + ((t > 0) ? lds[t - 1] : 0);
    #pragma unroll
    for (int i = 0; i < 4; ++i) {
        int idx = base + i;
        if (idx < P_TENSO) starts[idx] = run;
        run += v[i];
    }
}

// ---------------------------------------------------------------------------
// C: positions without atomics: pos = starts[tid] + rank. Reads only rt (4MB).
// ---------------------------------------------------------------------------
__global__ __launch_bounds__(256) void finalize_perm(
    const int* __restrict__ rt,
    const int* __restrict__ starts,
    int* __restrict__ perm)
{
    int n = blockIdx.x * 256 + threadIdx.x;
    if (n >= N_SAMP) return;
    const unsigned w = (unsigned)rt[n];
    int pos = starts[w >> 16] + (int)(w & 0xFFFFu);
    perm[pos] = n;           // random 4B into 4MB (L2-resident)
}

// ---------------------------------------------------------------------------
// Gather: 128-thread blocks, 2 tids/block (one per wave). Lanes = 32 samples
// x 2 channel-halves (R14 layout: 2 lanes/sample, 8 ch/lane, ONE dependent
// chain per lane). Block retires on max-of-2 (not max-of-4) tids => less
// tail-idle. perm prefetch one trip ahead; pairwise float2 result stores.
// ---------------------------------------------------------------------------
__global__ __launch_bounds__(128) void gather_phase(
    const float* __restrict__ trivecs,   // (P,16,3,8)
    const float* __restrict__ densities, // (P,16)
    const float* __restrict__ colors,    // (P,16,3)
    const int*   __restrict__ starts,
    const int*   __restrict__ counts,    // == cursor
    const int*   __restrict__ perm,
    const float4* __restrict__ pack,
    float* __restrict__ results_f)       // [n*4 + j], original order
{
    __shared__ __align__(16) float lds[2 * SLAB_F];
    const int lane = threadIdx.x & 63;
    const int wv   = threadIdx.x >> 6;
    const int t    = blockIdx.x * 2 + wv;
    if (t >= P_TENSO) return;

    const int start = starts[t];
    const int cnt   = counts[t];
    if (cnt == 0) return;

    float* slab = lds + wv * SLAB_F;
    float* dl   = slab + TV_F;
    float* cl   = dl + 16;

    const int pr = lane >> 1;   // sample slot 0..31
    const int h  = lane & 1;    // channel half (0: ch 0-7, 1: ch 8-15)
    const int hc = h * 8;       // channel base
    const int end = start + cnt;

    // trip-0 perm load issued before staging (flies under the slab loads)
    int p = start + pr;
    int n = perm[(p < end) ? p : (end - 1)];

    const float* tvg = trivecs + (size_t)t * 384;
    #pragma unroll
    for (int i = 0; i < 6; ++i) {
        int l = lane + i * 64;
        int c = l / 24;
        int rem = l - c * 24;
        slab[rem * ROW_STRIDE + c] = tvg[l];
    }
    if (lane < 16) dl[lane] = densities[(size_t)t * 16 + lane];
    if (lane < 48) {
        int c = lane / 3, k = lane - c * 3;
        cl[k * 16 + c] = colors[(size_t)t * 48 + lane];
    }

    // loop-invariant 8-channel slices (this lane's half)
    const float4 dnA = *(const float4*)(dl + hc);
    const float4 dnB = *(const float4*)(dl + hc + 4);
    const float4 c0A = *(const float4*)(cl + hc);
    const float4 c0B = *(const float4*)(cl + hc + 4);
    const float4 c1A = *(const float4*)(cl + 16 + hc);
    const float4 c1B = *(const float4*)(cl + 16 + hc + 4);
    const float4 c2A = *(const float4*)(cl + 32 + hc);
    const float4 c2B = *(const float4*)(cl + 32 + hc + 4);

    const int niter = (cnt + 31) >> 5;   // 32 samples per trip

    for (int it = 0; it < niter; ++it) {
        const bool valid = (p < end);
        const int sn = n;                 // saved for the store

        const float4 A = pack[(size_t)sn * 2 + 0];   // random 32B, pair-bcast
        const float4 B = pack[(size_t)sn * 2 + 1];

        if (it + 1 < niter) {             // prefetch next trip's perm
            p = start + (it + 1) * 32 + pr;
            n = perm[(p < end) ? p : (end - 1)];
        }

        const unsigned bits = __float_as_uint(B.z);

        float4 fA, fB;
        {
            const int is = bits & 7, il = (bits >> 9) & 7;
            const float4 vsA = *(const float4*)(slab + is * ROW_STRIDE + hc);
            const float4 vsB = *(const float4*)(slab + is * ROW_STRIDE + hc + 4);
            const float4 vlA = *(const float4*)(slab + il * ROW_STRIDE + hc);
            const float4 vlB = *(const float4*)(slab + il * ROW_STRIDE + hc + 4);
            fA.x = vsA.x * A.x + vlA.x * A.w;
            fA.y = vsA.y * A.x + vlA.y * A.w;
            fA.z = vsA.z * A.x + vlA.z * A.w;
            fA.w = vsA.w * A.x + vlA.w * A.w;
            fB.x = vsB.x * A.x + vlB.x * A.w;
            fB.y = vsB.y * A.x + vlB.y * A.w;
            fB.z = vsB.z * A.x + vlB.z * A.w;
            fB.w = vsB.w * A.x + vlB.w * A.w;
        }
        {
            const int is = (bits >> 3) & 7, il = (bits >> 12) & 7;
            const float4 vsA = *(const float4*)(slab + (8 + is) * ROW_STRIDE + hc);
            const float4 vsB = *(const float4*)(slab + (8 + is) * ROW_STRIDE + hc + 4);
            const float4 vlA = *(const float4*)(slab + (8 + il) * ROW_STRIDE + hc);
            const float4 vlB = *(const float4*)(slab + (8 + il) * ROW_STRIDE + hc + 4);
            fA.x *= vsA.x * A.y + vlA.x * B.x;
            fA.y *= vsA.y * A.y + vlA.y * B.x;
            fA.z *= vsA.z * A.y + vlA.z * B.x;
            fA.w *= vsA.w * A.y + vlA.w * B.x;
            fB.x *= vsB.x * A.y + vlB.x * B.x;
            fB.y *= vsB.y * A.y + vlB.y * B.x;
            fB.z *= vsB.z * A.y + vlB.z * B.x;
            fB.w *= vsB.w * A.y + vlB.w * B.x;
        }
        {
            const int is = (bits >> 6) & 7, il = (bits >> 15) & 7;
            const float4 vsA = *(const float4*)(slab + (16 + is) * ROW_STRIDE + hc);
            const float4 vsB = *(const float4*)(slab + (16 + is) * ROW_STRIDE + hc + 4);
            const float4 vlA = *(const float4*)(slab + (16 + il) * ROW_STRIDE + hc);
            const float4 vlB = *(const float4*)(slab + (16 + il) * ROW_STRIDE + hc + 4);
            fA.x *= vsA.x * A.z + vlA.x * B.y;
            fA.y *= vsA.y * A.z + vlA.y * B.y;
            fA.z *= vsA.z * A.z + vlA.z * B.y;
            fA.w *= vsA.w * A.z + vlA.w * B.y;
            fB.x *= vsB.x * A.z + vlB.x * B.y;
            fB.y *= vsB.y * A.z + vlB.y * B.y;
            fB.z *= vsB.z * A.z + vlB.z * B.y;
            fB.w *= vsB.w * A.z + vlB.w * B.y;
        }

        float s0 = fA.x*dnA.x + fA.y*dnA.y + fA.z*dnA.z + fA.w*dnA.w
                 + fB.x*dnB.x + fB.y*dnB.y + fB.z*dnB.z + fB.w*dnB.w;
        float s1 = fA.x*c0A.x + fA.y*c0A.y + fA.z*c0A.z + fA.w*c0A.w
                 + fB.x*c0B.x + fB.y*c0B.y + fB.z*c0B.z + fB.w*c0B.w;
        float s2 = fA.x*c1A.x + fA.y*c1A.y + fA.z*c1A.z + fA.w*c1A.w
                 + fB.x*c1B.x + fB.y*c1B.y + fB.z*c1B.z + fB.w*c1B.w;
        float s3 = fA.x*c2A.x + fA.y*c2A.y + fA.z*c2A.z + fA.w*c2A.w
                 + fB.x*c2B.x + fB.y*c2B.y + fB.z*c2B.z + fB.w*c2B.w;

        // cross-pair completion: one xor step
        s0 += __shfl_xor(s0, 1);
        s1 += __shfl_xor(s1, 1);
        s2 += __shfl_xor(s2, 1);
        s3 += __shfl_xor(s3, 1);

        float2 val;
        if (h == 0) {
            float dens = fmaxf(s0, 0.0f) + __logf(1.0f + __expf(-fabsf(s0)));
            val.x = -(dens * DENS_SCALE) * STEP_SZ;          // lt
            val.y = 1.0f / (1.0f + __expf(-s1));             // r
        } else {
            val.x = 1.0f / (1.0f + __expf(-s2));             // g
            val.y = 1.0f / (1.0f + __expf(-s3));             // b
        }
        if (valid) *(float2*)(results_f + (size_t)sn * 4 + 2 * h) = val;
    }
}

// ---------------------------------------------------------------------------
// E: 4 lanes per ray. Coalesced 64B loads per quad; quad prefix-product of
// exp(lt) via width-4 shfls (1 exp/lane/iter); ~3 iters instead of ~10.
// ---------------------------------------------------------------------------
__global__ __launch_bounds__(256) void ray_render(
    const float4* __restrict__ results,  // original n order
    const float*  __restrict__ t_min,
    const float*  __restrict__ bg,
    const int*    __restrict__ ray_start,
    const int*    __restrict__ step_id,
    float* __restrict__ out)
{
    const int lane = threadIdx.x & 63;
    const int g    = lane & 3;
    const int r    = (blockIdx.x * 256 + threadIdx.x) >> 2;
    if (r >= N_RAYS) return;
    const int s = ray_start[r];
    const int e = ray_start[r + 1];
    const float tmin_r = t_min[r];

    float eT = 1.0f, aR = 0.0f, aG = 0.0f, aB = 0.0f, aD = 0.0f;
    const int niter = (e - s + 3) >> 2;
    for (int it = 0; it < niter; ++it) {
        const int idx = s + it * 4 + g;
        const bool valid = (idx < e);
        const int ci = valid ? idx : (e - 1);
        const float4 res = results[ci];
        const float z = tmin_r + (float)step_id[ci] * STEP_SZ;
        const float elt = valid ? __expf(res.x) : 1.0f;   // exp(lt), 1 => w=0

        // exclusive prefix product of elt within the quad
        float excl = 1.0f;
        const float v1 = __shfl_up(elt, 1, 4); if (g >= 1) excl *= v1;
        const float v2 = __shfl_up(elt, 2, 4); if (g >= 2) excl *= v2;
        const float v3 = __shfl_up(elt, 3, 4); if (g >= 3) excl *= v3;

        const float w = eT * excl * (1.0f - elt);
        aR += w * res.y;
        aG += w * res.z;
        aB += w * res.w;
        aD += w * z;

        const float tot = __shfl(excl * elt, 3, 4);  // product of all 4 elts
        eT *= tot;
    }

    // quad reduction of accumulators
    aR += __shfl_xor(aR, 1); aR += __shfl_xor(aR, 2);
    aG += __shfl_xor(aG, 1); aG += __shfl_xor(aG, 2);
    aB += __shfl_xor(aB, 1); aB += __shfl_xor(aB, 2);
    aD += __shfl_xor(aD, 1); aD += __shfl_xor(aD, 2);

    const float outv = (g == 0) ? aR + eT * bg[0]
                     : (g == 1) ? aG + eT * bg[1]
                     : (g == 2) ? aB + eT * bg[2]
                     : aD;
    out[g * N_RAYS + r] = outv;
    if (g == 0) out[4 * N_RAYS + r] = 1.0f - eT;
}

// ---------------------------------------------------------------------------
// Fallback (ws too small): single fused kernel, original layouts.
// ---------------------------------------------------------------------------
__global__ __launch_bounds__(256) void trivec_render_fallback(
    const float* __restrict__ trivecs, const float* __restrict__ densities,
    const float* __restrict__ colors, const float* __restrict__ gws,
    const float* __restrict__ gwl, const float* __restrict__ t_min,
    const float* __restrict__ bg, const int* __restrict__ gis,
    const int* __restrict__ gil, const int* __restrict__ tenso_id,
    const int* __restrict__ ray_id, const int* __restrict__ step_id,
    float* __restrict__ out)
{
    const int lane = threadIdx.x & 63;
    const int r = blockIdx.x * 4 + (threadIdx.x >> 6);
    if (r >= N_RAYS) return;
    const int c = lane & 15;
    const int g = lane >> 4;
    int lo = 0, hi = N_SAMP;
    while (lo < hi) { int mid = (lo + hi) >> 1; if (ray_id[mid] < r) lo = mid + 1; else hi = mid; }
    const int seg_start = lo;
    hi = N_SAMP;
    while (lo < hi) { int mid = (lo + hi) >> 1; if (ray_id[mid] < r + 1) lo = mid + 1; else hi = mid; }
    const int seg_end = lo;
    const float tmin_r = t_min[r];
    float Tlog = 0.0f, accR = 0.0f, accG = 0.0f, accB = 0.0f, accD = 0.0f;
    const int niter = (seg_end - seg_start + 3) >> 2;
    for (int it = 0; it < niter; ++it) {
        const int n = seg_start + it * 4 + g;
        const bool valid = (n < seg_end);
        const int nc = valid ? n : (seg_end - 1);
        const int tid = tenso_id[nc];
        const float* tv = trivecs + (size_t)tid * 384 + c * 24;
        float f = 1.0f;
        #pragma unroll
        for (int a = 0; a < 3; ++a) {
            const int is = gis[nc*3+a], il = gil[nc*3+a];
            const float wS = gws[nc*3+a], wL = gwl[nc*3+a];
            f *= (tv[a*8+is] * wS + tv[a*8+il] * wL);
        }
        const float dns = densities[(size_t)tid * 16 + c];
        const float* colp = colors + ((size_t)tid * 16 + c) * 3;
        float s0 = f*dns, s1 = f*colp[0], s2 = f*colp[1], s3 = f*colp[2];
        #pragma unroll
        for (int m = 1; m < 16; m <<= 1) {
            s0 += __shfl_xor(s0, m); s1 += __shfl_xor(s1, m);
            s2 += __shfl_xor(s2, m); s3 += __shfl_xor(s3, m);
        }
        float dens = fmaxf(s0, 0.0f) + __logf(1.0f + __expf(-fabsf(s0)));
        const float lt = valid ? (-dens * STEP_SZ) : 0.0f;
        const float alpha = 1.0f - __expf(lt);
        const float rr = 1.0f/(1.0f+__expf(-s1)), gg = 1.0f/(1.0f+__expf(-s2)), bb = 1.0f/(1.0f+__expf(-s3));
        const float z = tmin_r + (float)step_id[nc] * STEP_SZ;
        const float lt0 = __shfl(lt,0), lt1 = __shfl(lt,16), lt2 = __shfl(lt,32), lt3 = __shfl(lt,48);
        float excl = Tlog;
        if (g > 0) excl += lt0;
        if (g > 1) excl += lt1;
        if (g > 2) excl += lt2;
        const float w = alpha * __expf(excl);
        Tlog += lt0 + lt1 + lt2 + lt3;
        accR += w*rr; accG += w*gg; accB += w*bb; accD += w*z;
    }
    accR += __shfl_xor(accR,16); accR += __shfl_xor(accR,32);
    accG += __shfl_xor(accG,16); accG += __shfl_xor(accG,32);
    accB += __shfl_xor(accB,16); accB += __shfl_xor(accB,32);
    accD += __shfl_xor(accD,16); accD += __shfl_xor(accD,32);
    const float bgw = __expf(Tlog);
    if (lane == 0) {
        out[0*N_RAYS+r] = accR + bgw*bg[0];
        out[1*N_RAYS+r] = accG + bgw*bg[1];
        out[2*N_RAYS+r] = accB + bgw*bg[2];
        out[3*N_RAYS+r] = accD;
        out[4*N_RAYS+r] = 1.0f - bgw;
    }
}

extern "C" void kernel_launch(void* const* d_in, const int* in_sizes, int n_in,
                              void* d_out, int out_size, void* d_ws, size_t ws_size,
                              hipStream_t stream) {
    const float* trivecs   = (const float*)d_in[0];
    const float* densities = (const float*)d_in[1];
    const float* colors    = (const float*)d_in[2];
    const float* gws       = (const float*)d_in[3];
    const float* gwl       = (const float*)d_in[4];
    const float* t_min     = (const float*)d_in[5];
    const float* bg        = (const float*)d_in[6];
    const int*   gis       = (const int*)d_in[7];
    const int*   gil       = (const int*)d_in[8];
    const int*   tenso_id  = (const int*)d_in[9];
    const int*   ray_id    = (const int*)d_in[10];
    const int*   step_id   = (const int*)d_in[11];
    float* out = (float*)d_out;

    if (ws_size < (size_t)WS_NEED) {
        trivec_render_fallback<<<(N_RAYS + 3) / 4, 256, 0, stream>>>(
            trivecs, densities, colors, gws, gwl, t_min, bg,
            gis, gil, tenso_id, ray_id, step_id, out);
        return;
    }

    char* ws = (char*)d_ws;
    float4* pack     = (float4*)(ws + OFF_PACK);
    float4* results  = (float4*)(ws + OFF_RESULTS);
    int*    perm     = (int*)(ws + OFF_PERM);
    int*    rt       = (int*)(ws + OFF_RT);
    int*    cursor   = (int*)(ws + OFF_CURSOR);
    int*    starts   = (int*)(ws + OFF_STARTS);
    int*    bsums    = (int*)(ws + OFF_BSUMS);
    int*    flag     = (int*)(ws + OFF_FLAG);
    int*    raystart = (int*)(ws + OFF_RSTART);

    // zero cursor + starts + bsums + flag in one async memset
    hipMemsetAsync(ws + OFF_CURSOR, 0, (OFF_FLAG + 64) - OFF_CURSOR, stream);

    pack_bounds_rank<<<(N_SAMP + 255) / 256, 256, 0, stream>>>(
        tenso_id, ray_id, gis, gil, gws, gwl, cursor, rt, raystart, pack);
    scan_fused<<<NB_SCAN, 256, 0, stream>>>(cursor, starts, bsums, flag);
    finalize_perm<<<(N_SAMP + 255) / 256, 256, 0, stream>>>(
        rt, starts, perm);
    gather_phase<<<(P_TENSO + 1) / 2, 128, 0, stream>>>(
        trivecs, densities, colors, starts, cursor, perm, pack, (float*)results);
    ray_render<<<(N_RAYS * 4 + 255) / 256, 256, 0, stream>>>(
        results, t_min, bg, raystart, step_id, out);
}